// Round 1
// baseline (87.437 us; speedup 1.0000x reference)
//
#include <hip/hip_runtime.h>
#include <math.h>

#define MIX_RADIUS 10
#define KSIZE 21           // 2*MIX_RADIUS + 1
#define BB 4
#define SS 128
#define HW4 4096           // H*W/4 = 128*128/4 float4 columns per s-plane
#define TS 16              // s-chunk per block
#define TPB 256

// out[b,s] = sum_k softmax(ada_mask[b,s,:])[k] * x[b, s+k-10]  (zero-padded in s)
// Register sliding window: each thread keeps 21 float4 x-values; each s-step
// issues 1 global_load_dwordx4, 84 v_fma_f32, 1 global_store_dwordx4.
__global__ __launch_bounds__(TPB, 2) void adaptive_mixing_kernel(
    const float* __restrict__ x,
    const float* __restrict__ ada_mask,
    float* __restrict__ out)
{
    __shared__ float sw[TS][KSIZE];

    const int tid = threadIdx.x;
    const int b   = blockIdx.z;
    const int s0  = blockIdx.y * TS;
    const int hw4 = blockIdx.x * TPB + tid;

    // --- per-row softmax for this block's TS rows (threads 0..TS-1) ---
    if (tid < TS) {
        const float* m = ada_mask + ((long)(b * SS + (s0 + tid))) * KSIZE;
        float v[KSIZE];
        float mx = -1e30f;
        #pragma unroll
        for (int k = 0; k < KSIZE; ++k) { v[k] = m[k]; mx = fmaxf(mx, v[k]); }
        float sum = 0.f;
        #pragma unroll
        for (int k = 0; k < KSIZE; ++k) { v[k] = __expf(v[k] - mx); sum += v[k]; }
        const float inv = 1.f / sum;
        #pragma unroll
        for (int k = 0; k < KSIZE; ++k) sw[tid][k] = v[k] * inv;
    }
    __syncthreads();

    const float4* x4   = (const float4*)x;
    float4*       out4 = (float4*)out;
    const long base = (long)b * SS * HW4 + hw4;

    // --- preload window: x(s0-10 .. s0+10), slot(sg) = (sg - s0 + 10) % 21 ---
    float4 win[KSIZE];
    #pragma unroll
    for (int i = 0; i < KSIZE; ++i) {
        const int sg = s0 - MIX_RADIUS + i;
        win[i] = (sg >= 0 && sg < SS) ? x4[base + (long)sg * HW4]
                                      : make_float4(0.f, 0.f, 0.f, 0.f);
    }

    // --- fully unrolled s-loop; all window indices static ---
    #pragma unroll
    for (int j = 0; j < TS; ++j) {
        float4 acc = make_float4(0.f, 0.f, 0.f, 0.f);
        #pragma unroll
        for (int k = 0; k < KSIZE; ++k) {
            const float  wgt = sw[j][k];              // wave-uniform broadcast
            const float4 xv  = win[(j + k) % KSIZE];  // x(s0+j-10+k)
            acc.x += wgt * xv.x;
            acc.y += wgt * xv.y;
            acc.z += wgt * xv.z;
            acc.w += wgt * xv.w;
        }
        out4[base + (long)(s0 + j) * HW4] = acc;

        if (j < TS - 1) {
            // replace oldest x(s0+j-10) with x(s0+j+11); both live in slot j%21
            const int sg = s0 + j + MIX_RADIUS + 1;
            win[j % KSIZE] = (sg < SS) ? x4[base + (long)sg * HW4]
                                       : make_float4(0.f, 0.f, 0.f, 0.f);
        }
    }
}

extern "C" void kernel_launch(void* const* d_in, const int* in_sizes, int n_in,
                              void* d_out, int out_size, void* d_ws, size_t ws_size,
                              hipStream_t stream) {
    const float* x    = (const float*)d_in[0];
    const float* mask = (const float*)d_in[1];
    float*       out  = (float*)d_out;

    dim3 grid(HW4 / TPB, SS / TS, BB);  // (16, 8, 4) = 512 blocks
    adaptive_mixing_kernel<<<grid, TPB, 0, stream>>>(x, mask, out);
}

// Round 3
// 87.230 us; speedup vs baseline: 1.0024x; 1.0024x over previous
//
#include <hip/hip_runtime.h>
#include <math.h>

#define MIX_RADIUS 10
#define KSIZE 21           // 2*MIX_RADIUS + 1
#define BB 4
#define SS 128
#define HW4 4096           // H*W/4 = 128*128/4 float4 columns per s-plane
#define TS 8               // s-chunk per block (halved from 16 for 2x grid parallelism)
#define TPB 256

typedef float f32x4 __attribute__((ext_vector_type(4)));  // clang-native for nontemporal builtin

// out[b,s] = sum_k softmax(ada_mask[b,s,:])[k] * x[b, s+k-10]  (zero-padded in s)
// Register sliding window: each thread keeps 21 float4 x-values; each s-step
// issues 1 global_load_dwordx4, 84 v_fma_f32, 1 nontemporal dwordx4 store.
// 1024 blocks -> 4 blocks/CU -> 16 waves/CU for latency hiding.
__global__ __launch_bounds__(TPB, 4) void adaptive_mixing_kernel(
    const float* __restrict__ x,
    const float* __restrict__ ada_mask,
    float* __restrict__ out)
{
    __shared__ float sw[TS][KSIZE];

    const int tid = threadIdx.x;
    const int b   = blockIdx.z;
    const int s0  = blockIdx.y * TS;
    const int hw4 = blockIdx.x * TPB + tid;

    // --- per-row softmax for this block's TS rows (threads 0..TS-1) ---
    if (tid < TS) {
        const float* m = ada_mask + ((long)(b * SS + (s0 + tid))) * KSIZE;
        float v[KSIZE];
        float mx = -1e30f;
        #pragma unroll
        for (int k = 0; k < KSIZE; ++k) { v[k] = m[k]; mx = fmaxf(mx, v[k]); }
        float sum = 0.f;
        #pragma unroll
        for (int k = 0; k < KSIZE; ++k) { v[k] = __expf(v[k] - mx); sum += v[k]; }
        const float inv = 1.f / sum;
        #pragma unroll
        for (int k = 0; k < KSIZE; ++k) sw[tid][k] = v[k] * inv;
    }
    __syncthreads();

    const f32x4* x4   = (const f32x4*)x;
    f32x4*       out4 = (f32x4*)out;
    const long base = (long)b * SS * HW4 + hw4;

    // --- preload window: x(s0-10 .. s0+10), slot(sg) = (sg - s0 + 10) % 21 ---
    f32x4 win[KSIZE];
    #pragma unroll
    for (int i = 0; i < KSIZE; ++i) {
        const int sg = s0 - MIX_RADIUS + i;
        win[i] = (sg >= 0 && sg < SS) ? x4[base + (long)sg * HW4]
                                      : (f32x4)(0.f);
    }

    // --- fully unrolled s-loop; all window indices static ---
    #pragma unroll
    for (int j = 0; j < TS; ++j) {
        f32x4 acc = (f32x4)(0.f);
        #pragma unroll
        for (int k = 0; k < KSIZE; ++k) {
            const float wgt = sw[j][k];               // wave-uniform broadcast
            acc += wgt * win[(j + k) % KSIZE];        // x(s0+j-10+k)
        }
        // write-once output: nontemporal store keeps L2/L3 for x halo reuse
        __builtin_nontemporal_store(acc, &out4[base + (long)(s0 + j) * HW4]);

        if (j < TS - 1) {
            // replace oldest x(s0+j-10) with x(s0+j+11); both live in slot j%21
            const int sg = s0 + j + MIX_RADIUS + 1;
            win[j % KSIZE] = (sg < SS) ? x4[base + (long)sg * HW4]
                                       : (f32x4)(0.f);
        }
    }
}

extern "C" void kernel_launch(void* const* d_in, const int* in_sizes, int n_in,
                              void* d_out, int out_size, void* d_ws, size_t ws_size,
                              hipStream_t stream) {
    const float* x    = (const float*)d_in[0];
    const float* mask = (const float*)d_in[1];
    float*       out  = (float*)d_out;

    dim3 grid(HW4 / TPB, SS / TS, BB);  // (16, 16, 4) = 1024 blocks
    adaptive_mixing_kernel<<<grid, TPB, 0, stream>>>(x, mask, out);
}

// Round 4
// 85.662 us; speedup vs baseline: 1.0207x; 1.0183x over previous
//
#include <hip/hip_runtime.h>
#include <math.h>

#define MIX_RADIUS 10
#define KSIZE 21           // 2*MIX_RADIUS + 1
#define BB 4
#define SS 128
#define HW4 4096           // H*W/4 = 128*128/4 float4 columns per s-plane
#define TS 8               // outputs per thread along s
#define NPLANES (TS + 2 * MIX_RADIUS)  // 28 input planes per thread
#define TPB 256

typedef float f32x4 __attribute__((ext_vector_type(4)));

// out[b,s] = sum_k softmax(ada_mask[b,s,:])[k] * x[b, s+k-10]  (zero-padded in s)
// Preload-all structure: each thread issues ALL 28 plane loads (28 KB/wave in
// flight -> guaranteed HBM saturation by Little's law), then computes 8 outputs
// back-to-back (84 v_fma_f32 each) with nontemporal dwordx4 stores.
// 112 VGPR window + ~12 misc fits the <=128 VGPR tier: 16 waves/CU.
__global__ __launch_bounds__(TPB, 4) void adaptive_mixing_kernel(
    const float* __restrict__ x,
    const float* __restrict__ ada_mask,
    float* __restrict__ out)
{
    __shared__ float sw[TS][KSIZE];

    const int tid = threadIdx.x;
    const int b   = blockIdx.z;
    const int s0  = blockIdx.y * TS;
    const int hw4 = blockIdx.x * TPB + tid;

    // --- per-row softmax for this block's TS rows (threads 0..TS-1) ---
    if (tid < TS) {
        const float* m = ada_mask + ((long)(b * SS + (s0 + tid))) * KSIZE;
        float v[KSIZE];
        float mx = -1e30f;
        #pragma unroll
        for (int k = 0; k < KSIZE; ++k) { v[k] = m[k]; mx = fmaxf(mx, v[k]); }
        float sum = 0.f;
        #pragma unroll
        for (int k = 0; k < KSIZE; ++k) { v[k] = __expf(v[k] - mx); sum += v[k]; }
        const float inv = 1.f / sum;
        #pragma unroll
        for (int k = 0; k < KSIZE; ++k) sw[tid][k] = v[k] * inv;
    }
    __syncthreads();

    const f32x4* x4   = (const f32x4*)x;
    f32x4*       out4 = (f32x4*)out;
    const long base = (long)b * SS * HW4 + hw4;

    // --- issue ALL 28 plane loads up front (indices static after unroll) ---
    f32x4 win[NPLANES];
    #pragma unroll
    for (int i = 0; i < NPLANES; ++i) {
        const int sg = s0 - MIX_RADIUS + i;          // s0-10 .. s0+17
        win[i] = (sg >= 0 && sg < SS) ? x4[base + (long)sg * HW4]
                                      : (f32x4)(0.f);
    }

    // --- 8 outputs, 84 FMAs each; acc registers reused across j ---
    #pragma unroll
    for (int j = 0; j < TS; ++j) {
        f32x4 acc = (f32x4)(0.f);
        #pragma unroll
        for (int k = 0; k < KSIZE; ++k) {
            const float wgt = sw[j][k];   // wave-uniform LDS broadcast
            acc += wgt * win[j + k];      // x(s0+j-10+k)
        }
        // write-once output: nontemporal store keeps L2/L3 for x halo reuse
        __builtin_nontemporal_store(acc, &out4[base + (long)(s0 + j) * HW4]);
    }
}

extern "C" void kernel_launch(void* const* d_in, const int* in_sizes, int n_in,
                              void* d_out, int out_size, void* d_ws, size_t ws_size,
                              hipStream_t stream) {
    const float* x    = (const float*)d_in[0];
    const float* mask = (const float*)d_in[1];
    float*       out  = (float*)d_out;

    dim3 grid(HW4 / TPB, SS / TS, BB);  // (16, 16, 4) = 1024 blocks
    adaptive_mixing_kernel<<<grid, TPB, 0, stream>>>(x, mask, out);
}